// Round 11
// baseline (2373.064 us; speedup 1.0000x reference)
//
#include <hip/hip_runtime.h>

#define TMAIN 1024
#define TFUT  64
#define TTOT  (TMAIN + TFUT)

// wave-uniform broadcast of lane k (literal 0..31) -> SGPR operand for v_fmac
#define RL(v,k) __uint_as_float(__builtin_amdgcn_readlane(__float_as_uint(v),(k)))
// DPP cross-lane on the VALU pipe
#define DPPF(v,ctrl) __int_as_float(__builtin_amdgcn_update_dpp(0, __float_as_int(v), (ctrl), 0xf, 0xf, true))
#define DPPADD(d,ctrl,rm) d += __int_as_float(__builtin_amdgcn_update_dpp(0, __float_as_int(d), (ctrl), (rm), 0xf, true));

// 8 NAMED float4 locals per matrix slice (no arrays -> nothing scratch-indexable)
#define LD8(N,P) \
  float4 N##0=(P)[0], N##1=(P)[1], N##2=(P)[2], N##3=(P)[3], \
         N##4=(P)[4], N##5=(P)[5], N##6=(P)[6], N##7=(P)[7];
#define PIN(v) asm volatile("" : "+v"(v.x), "+v"(v.y), "+v"(v.z), "+v"(v.w));
#define PIN8(N) PIN(N##0) PIN(N##1) PIN(N##2) PIN(N##3) PIN(N##4) PIN(N##5) PIN(N##6) PIN(N##7)

#define D4(W,k,hv) \
  a0 = fmaf(RL(hv,(k)+0), W.x, a0); \
  a1 = fmaf(RL(hv,(k)+1), W.y, a1); \
  a2 = fmaf(RL(hv,(k)+2), W.z, a2); \
  a3 = fmaf(RL(hv,(k)+3), W.w, a3);
#define DOT32(N,hv) \
  D4(N##0,0,hv)  D4(N##1,4,hv)  D4(N##2,8,hv)  D4(N##3,12,hv) \
  D4(N##4,16,hv) D4(N##5,20,hv) D4(N##6,24,hv) D4(N##7,28,hv)

// 512 threads = 8 waves. half = tid>>8 (k-group), waves 0-3 = k[0,32), 4-7 = k[32,64).
// Within a group: lane = u_lo*4+q (gate in lane bits 0-1, DPP quad exchange),
// unit = wq*16 + lane>>2, row = q*64+unit. Thread owns 96 weight floats
// (24 named float4) -> pressure ~120 VGPR fits the compiler's 128 budget, so
// weights stay register-resident WITHOUT fighting the occupancy heuristic.
// h distributed in lanes; each group reads h LDS-rotated by its k-offset so
// all readlane indices are literals 0..31. 4 barriers/step.
__global__ __launch_bounds__(512, 4)
void lstm2_kernel(const float* __restrict__ x,
                  const float* __restrict__ Wih1,
                  const float* __restrict__ Whh1,
                  const float* __restrict__ bih1,
                  const float* __restrict__ bhh1,
                  const float* __restrict__ Wih2,
                  const float* __restrict__ Whh2,
                  const float* __restrict__ bih2,
                  const float* __restrict__ bhh2,
                  const float* __restrict__ Wl,
                  const float* __restrict__ bl,
                  float* __restrict__ out)
{
    const int b    = blockIdx.x;
    const int tid  = threadIdx.x;
    const int half = tid >> 8;                 // k-group (wave-uniform)
    const int lane = tid & 63;
    const int wq   = (tid >> 6) & 3;           // wave index within group
    const int q    = lane & 3;                 // gate 0..3 (i,f,g,o)
    const int unit = (wq << 4) | (lane >> 2);  // hidden unit 0..63
    const int row  = (q << 6) | unit;          // gate-row 0..255
    const int pidx = (unit << 2) | q;          // conflict-free partial index
    const int koff = half << 5;                // 0 or 32

    const float4* pA = reinterpret_cast<const float4*>(Whh1 + row * 64 + koff);
    const float4* pB = reinterpret_cast<const float4*>(Wih2 + row * 64 + koff);
    const float4* pC = reinterpret_cast<const float4*>(Whh2 + row * 64 + koff);
    LD8(A, pA) LD8(B, pB) LD8(C, pC)
    PIN8(A) PIN8(B) PIN8(C)

    const float wih1r = Wih1[row];
    const float bias1 = bih1[row] + bhh1[row];
    const float bias2 = bih2[row] + bhh2[row];
    const float wl_l  = Wl[lane];
    const float bl0   = bl[0];

    __shared__ float part1[256], part2[256], part3[256];
    __shared__ float h1buf[64], h2buf[64];

    float vh1 = 0.f, vh2 = 0.f, c1 = 0.f, c2 = 0.f, xv = 0.f;
    const float* xb = x + b * TMAIN;
    float* ob = out + b * TTOT;

    for (int s = 0; s < TTOT; ++s) {
        // -------- Phase A (both groups): L1 half-dot + Whh2 half-dot --------
        float a0 = 0.f, a1 = 0.f, a2 = 0.f, a3 = 0.f;
        DOT32(A, vh1)
        const float p1 = (a0 + a1) + (a2 + a3);
        a0 = 0.f; a1 = 0.f; a2 = 0.f; a3 = 0.f;
        DOT32(C, vh2)
        const float p2 = (a0 + a1) + (a2 + a3);
        if (half) { part1[pidx] = p1; part2[pidx] = p2; }
        __syncthreads();                               // B1: partials 1,2 ready

        // -------- Phase B (group 0): layer-1 activation --------
        if (!half) {
            const float x_t = (s < TMAIN) ? xb[s] : xv;
            float acc = p1 + part1[pidx] + fmaf(wih1r, x_t, bias1);
            float earg = (q == 2) ? -2.f * acc : -acc;
            float r  = __builtin_amdgcn_rcpf(1.f + __expf(earg));
            float gv = (q == 2) ? fmaf(2.f, r, -1.f) : r;   // tanh for g, sigma else
            float u1 = DPPF(gv, 0xB1), u2 = DPPF(gv, 0x4E), u3 = DPPF(gv, 0x1B);
            float gi = (q==0)?gv : (q==1)?u1 : (q==2)?u2 : u3;
            float gf = (q==1)?gv : (q==0)?u1 : (q==3)?u2 : u3;
            float gg = (q==2)?gv : (q==3)?u1 : (q==0)?u2 : u3;
            float go = (q==3)?gv : (q==2)?u1 : (q==1)?u2 : u3;
            c1 = fmaf(gf, c1, gi * gg);
            float tr = __builtin_amdgcn_rcpf(1.f + __expf(-2.f * c1));
            float h1n = go * fmaf(2.f, tr, -1.f);
            if (q == 0) h1buf[unit] = h1n;
        }
        __syncthreads();                               // B2: h1_new ready
        vh1 = h1buf[(lane + koff) & 63];               // rotated for group 1

        // -------- Phase C (both groups): Wih2 half-dot on h1_new --------
        a0 = 0.f; a1 = 0.f; a2 = 0.f; a3 = 0.f;
        DOT32(B, vh1)
        const float p3 = (a0 + a1) + (a2 + a3);
        if (half) part3[pidx] = p3;
        __syncthreads();                               // B3: partial 3 ready

        // -------- Phase D (group 0): layer-2 activation --------
        if (!half) {
            float acc = p2 + part2[pidx] + p3 + part3[pidx] + bias2;
            float earg = (q == 2) ? -2.f * acc : -acc;
            float r  = __builtin_amdgcn_rcpf(1.f + __expf(earg));
            float gv = (q == 2) ? fmaf(2.f, r, -1.f) : r;
            float u1 = DPPF(gv, 0xB1), u2 = DPPF(gv, 0x4E), u3 = DPPF(gv, 0x1B);
            float gi = (q==0)?gv : (q==1)?u1 : (q==2)?u2 : u3;
            float gf = (q==1)?gv : (q==0)?u1 : (q==3)?u2 : u3;
            float gg = (q==2)?gv : (q==3)?u1 : (q==0)?u2 : u3;
            float go = (q==3)?gv : (q==2)?u1 : (q==1)?u2 : u3;
            c2 = fmaf(gf, c2, gi * gg);
            float tr = __builtin_amdgcn_rcpf(1.f + __expf(-2.f * c2));
            float h2n = go * fmaf(2.f, tr, -1.f);
            if (q == 0) h2buf[unit] = h2n;
        }
        __syncthreads();                               // B4: h2_new ready
        vh2 = h2buf[(lane + koff) & 63];               // rotated for group 1

        // -------- Phase E (group 0): output xv = Wl . h2_new + bl --------
        if (!half) {
            float rs = wl_l * vh2;                     // koff=0: unrotated pairing
            DPPADD(rs, 0x111, 0xf)   // row_shr:1
            DPPADD(rs, 0x112, 0xf)   // row_shr:2
            DPPADD(rs, 0x114, 0xf)   // row_shr:4
            DPPADD(rs, 0x118, 0xf)   // row_shr:8
            DPPADD(rs, 0x142, 0xa)   // row_bcast15 -> rows 1,3
            DPPADD(rs, 0x143, 0xc)   // row_bcast31 -> rows 2,3
            xv = RL(rs, 63) + bl0;
            if (tid == 0) ob[s] = xv;
        }
    }
}

extern "C" void kernel_launch(void* const* d_in, const int* in_sizes, int n_in,
                              void* d_out, int out_size, void* d_ws, size_t ws_size,
                              hipStream_t stream)
{
    const float* xx   = (const float*)d_in[0];
    const float* Wih1 = (const float*)d_in[1];
    const float* Whh1 = (const float*)d_in[2];
    const float* bih1 = (const float*)d_in[3];
    const float* bhh1 = (const float*)d_in[4];
    const float* Wih2 = (const float*)d_in[5];
    const float* Whh2 = (const float*)d_in[6];
    const float* bih2 = (const float*)d_in[7];
    const float* bhh2 = (const float*)d_in[8];
    const float* Wl   = (const float*)d_in[9];
    const float* bl   = (const float*)d_in[10];
    float* out = (float*)d_out;

    lstm2_kernel<<<dim3(512), dim3(512), 0, stream>>>(
        xx, Wih1, Whh1, bih1, bhh1, Wih2, Whh2, bih2, bhh2, Wl, bl, out);
}